// Round 8
// baseline (3240.297 us; speedup 1.0000x reference)
//
#include <hip/hip_runtime.h>
#include <hip/hip_cooperative_groups.h>
#include <math.h>
#include <cstddef>

namespace cg = cooperative_groups;

#define EPS 1e-5f
#define NBLK 512

typedef __attribute__((ext_vector_type(8))) short bf16x8;
typedef __attribute__((ext_vector_type(4))) float f32x4;

__device__ __forceinline__ float wave_sum(float v) {
#pragma unroll
  for (int o = 32; o > 0; o >>= 1) v += __shfl_xor(v, o, 64);
  return v;
}

__device__ __forceinline__ unsigned short f2b(float f) {
  union { float f; unsigned int u; } v; v.f = f;
  unsigned int r = (v.u + 0x7FFFu + ((v.u >> 16) & 1u)) >> 16;
  return (unsigned short)r;
}
__device__ __forceinline__ float b2f(unsigned short u) {
  union { unsigned int u; float f; } v; v.u = ((unsigned int)u) << 16;
  return v.f;
}
__device__ __forceinline__ unsigned int pk2(float lo, float hi) {
  unsigned int r;
  asm volatile("v_cvt_pk_bf16_f32 %0, %1, %2" : "=v"(r) : "v"(lo), "v"(hi));
  return r;
}

// Shared-memory budget: gemm32 = 2*32*72 + 2*64*72 shorts = 27648 B
//                       attn8  = 2*64*72 shorts + 64*36 uint = 27648 B
#define SM_SHORTS 13824

// ============ All arguments for the fused kernel ===========================
struct FusedArgs {
  const float* csrc[8]; unsigned short* cdst[8]; int cn[8];  // conv
  const float* x;
  const unsigned short* reduce_wb; const float* reduce_b;
  const unsigned short* in_wb;  const float* in_b;
  const unsigned short* out_wb; const float* out_b;
  const unsigned short* ff1_wb; const float* ff1_b;
  const unsigned short* ff2_wb; const float* ff2_b;
  const float* ln1_w; const float* ln1_b;
  const float* ln2_w; const float* ln2_b;
  const unsigned short* mlp_w1b; const float* mlp_b1;
  const unsigned short* mlp_w2b; const float* mlp_b2;
  const unsigned short* mlp_w3b; const float* mlp_b3;
  const float* hi; const float* ne;
  float* feat0_f; unsigned short* feat0_b;
  float* feat_f;  unsigned short* feat_b;
  float* tmp_f;   float* pm;
  unsigned short* qkv_b; unsigned short* relu_b; unsigned short* po_b;
  unsigned short* relu2_b;
  float* featq_f; float* out;
};

// ============ Phase device functions (bodies identical to R1 kernels) ======
__device__ __forceinline__ void conv_dev(int bx, int arr, const FusedArgs& a) {
  const int i = (bx * 256 + (int)threadIdx.x) * 4;
  if (i < a.cn[arr]) {
    const float4 f = *(const float4*)(a.csrc[arr] + i);
    unsigned short t[4] = {f2b(f.x), f2b(f.y), f2b(f.z), f2b(f.w)};
    unsigned short* d = a.cdst[arr] + i;
    *(ushort2*)d = *(ushort2*)&t[0];
    *(ushort2*)(d + 2) = *(ushort2*)&t[2];
  }
}

template <int RELU, int AF32, int OUT_F32, int OUT_BF16, int MERGE, int RESID,
          int SCALEQ>
__device__ void gemm32_dev(unsigned short* smbase, int bx, int by,
                           const void* Aptr, const float* pmp,
                           const unsigned short* W, const float* bias,
                           const float* Rf, float* Cf, unsigned short* Cb,
                           int N, int K) {
  typedef unsigned short (*AsT)[32][72];
  typedef unsigned short (*WsT)[64][72];
  AsT As = (AsT)smbase;                 // [2][32][72]
  WsT Ws = (WsT)(smbase + 2 * 32 * 72); // [2][64][72]
  const int tid = threadIdx.x;
  const int wid = tid >> 6, lane = tid & 63;
  const int ln = lane & 15, quad = lane >> 4;
  const int m0 = bx * 32, n0 = by * 64;
  const int arow = tid >> 3, aseg = tid & 7;
  const int wrow = tid >> 2, wseg = tid & 3;
  const int KS = K >> 6;

  bf16x8 ra;
  float4 ra32[2];
  bf16x8 rwb0, rwb1;
  bf16x8 rp[4];
  float rl;

  auto load_tile = [&](int ks) {
    const int k0 = ks * 64;
    if (MERGE) {
      const int h = ks;
      const int row = m0 + arow;
      rl = 0.f;
#pragma unroll
      for (int s = 0; s < 4; ++s) {
        const size_t bb = (size_t)((s * 8 + h) * 2048 + row);
        rl += pmp[bb];
        rp[s] = *(const bf16x8*)((const unsigned short*)Aptr + bb * 64 + aseg * 8);
      }
    } else if (AF32) {
      const float* ap = (const float*)Aptr + (size_t)(m0 + arow) * K + k0 + aseg * 8;
      ra32[0] = *(const float4*)ap;
      ra32[1] = *(const float4*)(ap + 4);
    } else {
      ra = *(const bf16x8*)((const unsigned short*)Aptr +
                            (size_t)(m0 + arow) * K + k0 + aseg * 8);
    }
    const unsigned short* wp = W + (size_t)(n0 + wrow) * K + k0 + wseg * 16;
    rwb0 = *(const bf16x8*)wp;
    rwb1 = *(const bf16x8*)(wp + 8);
  };

  auto store_tile = [&](int buf) {
    if (MERGE) {
      float inv = 1.f / rl;
      unsigned short ta[8];
#pragma unroll
      for (int j = 0; j < 8; ++j) {
        float s = b2f((unsigned short)rp[0][j]) + b2f((unsigned short)rp[1][j]) +
                  b2f((unsigned short)rp[2][j]) + b2f((unsigned short)rp[3][j]);
        ta[j] = f2b(inv * s);
      }
      *(bf16x8*)&As[buf][arow][aseg * 8] = *(const bf16x8*)&ta[0];
    } else if (AF32) {
      unsigned short ta[8];
      ta[0] = f2b(ra32[0].x); ta[1] = f2b(ra32[0].y);
      ta[2] = f2b(ra32[0].z); ta[3] = f2b(ra32[0].w);
      ta[4] = f2b(ra32[1].x); ta[5] = f2b(ra32[1].y);
      ta[6] = f2b(ra32[1].z); ta[7] = f2b(ra32[1].w);
      *(bf16x8*)&As[buf][arow][aseg * 8] = *(const bf16x8*)&ta[0];
    } else {
      *(bf16x8*)&As[buf][arow][aseg * 8] = ra;
    }
    *(bf16x8*)&Ws[buf][wrow][wseg * 16] = rwb0;
    *(bf16x8*)&Ws[buf][wrow][wseg * 16 + 8] = rwb1;
  };

  f32x4 acc[2];
  acc[0] = (f32x4){0.f, 0.f, 0.f, 0.f};
  acc[1] = (f32x4){0.f, 0.f, 0.f, 0.f};
  const int mrow = (wid & 1) * 16, nh = wid >> 1;

  load_tile(0);
  store_tile(0);
  __syncthreads();

#pragma unroll 1
  for (int ks = 0; ks < KS; ++ks) {
    const int cur = ks & 1;
    if (ks + 1 < KS) load_tile(ks + 1);
#pragma unroll
    for (int kc = 0; kc < 2; ++kc) {
      bf16x8 af = *(const bf16x8*)&As[cur][mrow + ln][kc * 32 + quad * 8];
#pragma unroll
      for (int nt = 0; nt < 2; ++nt) {
        bf16x8 wf = *(const bf16x8*)&Ws[cur][nh * 32 + nt * 16 + ln][kc * 32 + quad * 8];
        acc[nt] = __builtin_amdgcn_mfma_f32_16x16x32_bf16(af, wf, acc[nt], 0, 0, 0);
      }
    }
    if (ks + 1 < KS) store_tile(cur ^ 1);
    __syncthreads();
  }

  const int gm = m0 + mrow + quad * 4;
  const float qs = (SCALEQ && n0 < 512) ? 0.125f : 1.f;
#pragma unroll
  for (int nt = 0; nt < 2; ++nt) {
    const int gn = n0 + nh * 32 + nt * 16 + ln;
    float bv = bias[gn];
#pragma unroll
    for (int r = 0; r < 4; ++r) {
      float v = acc[nt][r] + bv;
      if (SCALEQ) v *= qs;
      if (RELU) v = fmaxf(v, 0.f);
      if (RESID) v += Rf[(size_t)(gm + r) * N + gn];
      if (OUT_F32) Cf[(size_t)(gm + r) * N + gn] = v;
      if (OUT_BF16) Cb[(size_t)(gm + r) * N + gn] = f2b(v);
    }
  }
}

__device__ void attn8_dev(unsigned short* smbase, int qt, int h, int sp,
                          const unsigned short* qkv, float* pm,
                          unsigned short* po) {
  typedef unsigned short (*KVT)[72];
  typedef unsigned int (*PpT)[36];
  KVT Ks = (KVT)smbase;                  // [64][72]
  KVT Vt = (KVT)(smbase + 64 * 72);      // [64][72]
  PpT Pp = (PpT)(smbase + 2 * 64 * 72);  // [64][36] uint
  const int tid = threadIdx.x;
  const int wid = tid >> 6, lane = tid & 63;
  const int ln = lane & 15, quad = lane >> 4;
  const int wq0 = wid * 16;

  bf16x8 aq[2];
  {
    const unsigned short* qp =
        qkv + (size_t)(qt * 64 + wq0 + ln) * 1536 + h * 64 + quad * 8;
    aq[0] = *(const bf16x8*)qp;
    aq[1] = *(const bf16x8*)(qp + 32);
  }

  const int key = tid >> 2, seg = tid & 3;
  bf16x8 rk0, rk1;
  unsigned short tv[16];

  auto load_kv = [&](int t) {
    const int g = sp * 8 + t;
    const unsigned short* kr =
        qkv + (size_t)(g * 64 + key) * 1536 + 512 + h * 64 + seg * 16;
    rk0 = *(const bf16x8*)kr;
    rk1 = *(const bf16x8*)(kr + 8);
#pragma unroll
    for (int j = 0; j < 16; ++j)
      tv[j] = qkv[(size_t)(g * 64 + wid * 16 + j) * 1536 + 1024 + h * 64 + lane];
  };
  auto store_kv = [&]() {
    *(bf16x8*)&Ks[key][seg * 16] = rk0;
    *(bf16x8*)&Ks[key][seg * 16 + 8] = rk1;
    *(bf16x8*)&Vt[lane][wid * 16] = *(const bf16x8*)&tv[0];
    *(bf16x8*)&Vt[lane][wid * 16 + 8] = *(const bf16x8*)&tv[8];
  };

  float l_r = 0.f;
  f32x4 acc_o[4];
#pragma unroll
  for (int nt = 0; nt < 4; ++nt) acc_o[nt] = (f32x4){0.f, 0.f, 0.f, 0.f};

  load_kv(0);
  store_kv();
  __syncthreads();

#pragma unroll 1
  for (int t = 0; t < 8; ++t) {
    if (t + 1 < 8) load_kv(t + 1);

    f32x4 s_acc[4];
#pragma unroll
    for (int nt = 0; nt < 4; ++nt) s_acc[nt] = (f32x4){0.f, 0.f, 0.f, 0.f};
#pragma unroll
    for (int nt = 0; nt < 4; ++nt) {
      bf16x8 kf0 = *(const bf16x8*)&Ks[nt * 16 + ln][quad * 8];
      bf16x8 kf1 = *(const bf16x8*)&Ks[nt * 16 + ln][32 + quad * 8];
      s_acc[nt] = __builtin_amdgcn_mfma_f32_16x16x32_bf16(kf0, aq[0], s_acc[nt], 0, 0, 0);
      s_acc[nt] = __builtin_amdgcn_mfma_f32_16x16x32_bf16(kf1, aq[1], s_acc[nt], 0, 0, 0);
    }

#pragma unroll
    for (int nt = 0; nt < 4; ++nt) {
      float p0 = __expf(s_acc[nt][0]);
      float p1 = __expf(s_acc[nt][1]);
      float p2 = __expf(s_acc[nt][2]);
      float p3 = __expf(s_acc[nt][3]);
      l_r += (p0 + p1) + (p2 + p3);
      uint2 w;
      w.x = pk2(p0, p1);
      w.y = pk2(p2, p3);
      *(uint2*)&Pp[wq0 + ln][nt * 8 + quad * 2] = w;
    }

#pragma unroll
    for (int kc = 0; kc < 2; ++kc) {
      bf16x8 pf = *(const bf16x8*)&Pp[wq0 + ln][kc * 16 + quad * 4];
#pragma unroll
      for (int nt = 0; nt < 4; ++nt) {
        bf16x8 vf = *(const bf16x8*)&Vt[nt * 16 + ln][kc * 32 + quad * 8];
        acc_o[nt] = __builtin_amdgcn_mfma_f32_16x16x32_bf16(pf, vf, acc_o[nt], 0, 0, 0);
      }
    }
    __syncthreads();
    if (t + 1 < 8) {
      store_kv();
      __syncthreads();
    }
  }

  const size_t base = (size_t)((sp * 8 + h) * 2048 + qt * 64);
  float l = l_r;
  l += __shfl_xor(l, 16, 64);
  l += __shfl_xor(l, 32, 64);
  if (quad == 0) pm[base + wq0 + ln] = l;
#pragma unroll
  for (int r = 0; r < 4; ++r) {
    const size_t row = base + wq0 + quad * 4 + r;
#pragma unroll
    for (int nt = 0; nt < 4; ++nt)
      po[row * 64 + nt * 16 + ln] = f2b(acc_o[nt][r]);
  }
}

__device__ void inorm512_dev(int bx, float* dst, unsigned short* dstb,
                             const float* src) {
  const int row = bx * 4 + ((int)threadIdx.x >> 6);
  const int lane = threadIdx.x & 63;
  const float4* s = (const float4*)(src + (size_t)row * 512);
  float4 a = s[lane], b = s[lane + 64];
  float sum = a.x + a.y + a.z + a.w + b.x + b.y + b.z + b.w;
  float mean = wave_sum(sum) * (1.f / 512.f);
  float vs = (a.x - mean) * (a.x - mean) + (a.y - mean) * (a.y - mean) +
             (a.z - mean) * (a.z - mean) + (a.w - mean) * (a.w - mean) +
             (b.x - mean) * (b.x - mean) + (b.y - mean) * (b.y - mean) +
             (b.z - mean) * (b.z - mean) + (b.w - mean) * (b.w - mean);
  float rs = rsqrtf(wave_sum(vs) * (1.f / 512.f) + EPS);
  float4 oa, obv;
  oa.x = (a.x - mean) * rs; oa.y = (a.y - mean) * rs;
  oa.z = (a.z - mean) * rs; oa.w = (a.w - mean) * rs;
  obv.x = (b.x - mean) * rs; obv.y = (b.y - mean) * rs;
  obv.z = (b.z - mean) * rs; obv.w = (b.w - mean) * rs;
  float4* d = (float4*)(dst + (size_t)row * 512);
  d[lane] = oa; d[lane + 64] = obv;
  unsigned short* db = dstb + (size_t)row * 512;
  unsigned short t0[4] = {f2b(oa.x), f2b(oa.y), f2b(oa.z), f2b(oa.w)};
  unsigned short t1[4] = {f2b(obv.x), f2b(obv.y), f2b(obv.z), f2b(obv.w)};
  *(ushort2*)&db[lane * 4] = *(ushort2*)&t0[0];
  *(ushort2*)&db[lane * 4 + 2] = *(ushort2*)&t0[2];
  *(ushort2*)&db[256 + lane * 4] = *(ushort2*)&t1[0];
  *(ushort2*)&db[256 + lane * 4 + 2] = *(ushort2*)&t1[2];
}

__device__ void ln_res2_dev(int bx, float* dst, unsigned short* dstb,
                            const float* src, const float* w, const float* bb) {
  const int row = bx * 4 + ((int)threadIdx.x >> 6);
  const int lane = threadIdx.x & 63;
  const float4* xs = (const float4*)(src + (size_t)row * 512);
  float4 a = xs[lane], b = xs[lane + 64];
  float sum = a.x + a.y + a.z + a.w + b.x + b.y + b.z + b.w;
  float mean = wave_sum(sum) * (1.f / 512.f);
  float vs = (a.x - mean) * (a.x - mean) + (a.y - mean) * (a.y - mean) +
             (a.z - mean) * (a.z - mean) + (a.w - mean) * (a.w - mean) +
             (b.x - mean) * (b.x - mean) + (b.y - mean) * (b.y - mean) +
             (b.z - mean) * (b.z - mean) + (b.w - mean) * (b.w - mean);
  float rs = rsqrtf(wave_sum(vs) * (1.f / 512.f) + EPS);
  float4 wa = ((const float4*)w)[lane], wb = ((const float4*)w)[lane + 64];
  float4 ba = ((const float4*)bb)[lane], bbv = ((const float4*)bb)[lane + 64];
  float4 oa, ob2;
  oa.x = (a.x - mean) * rs * wa.x + ba.x; oa.y = (a.y - mean) * rs * wa.y + ba.y;
  oa.z = (a.z - mean) * rs * wa.z + ba.z; oa.w = (a.w - mean) * rs * wa.w + ba.w;
  ob2.x = (b.x - mean) * rs * wb.x + bbv.x; ob2.y = (b.y - mean) * rs * wb.y + bbv.y;
  ob2.z = (b.z - mean) * rs * wb.z + bbv.z; ob2.w = (b.w - mean) * rs * wb.w + bbv.w;
  float4* d = (float4*)(dst + (size_t)row * 512);
  d[lane] = oa; d[lane + 64] = ob2;
  unsigned short* dbp = dstb + (size_t)row * 512;
  unsigned short t0[4] = {f2b(oa.x), f2b(oa.y), f2b(oa.z), f2b(oa.w)};
  unsigned short t1[4] = {f2b(ob2.x), f2b(ob2.y), f2b(ob2.z), f2b(ob2.w)};
  *(ushort2*)&dbp[lane * 4] = *(ushort2*)&t0[0];
  *(ushort2*)&dbp[lane * 4 + 2] = *(ushort2*)&t0[2];
  *(ushort2*)&dbp[256 + lane * 4] = *(ushort2*)&t1[0];
  *(ushort2*)&dbp[256 + lane * 4 + 2] = *(ushort2*)&t1[2];
}

__device__ void add_inorm_dev(int bx, float* feat, unsigned short* featb,
                              const float* feat0) {
  const int row = bx * 4 + ((int)threadIdx.x >> 6);
  const int lane = threadIdx.x & 63;
  float4* f = (float4*)(feat + (size_t)row * 512);
  const float4* f0 = (const float4*)(feat0 + (size_t)row * 512);
  float4 a = f[lane], b = f[lane + 64];
  float sum = a.x + a.y + a.z + a.w + b.x + b.y + b.z + b.w;
  float mean = wave_sum(sum) * (1.f / 512.f);
  float vs = (a.x - mean) * (a.x - mean) + (a.y - mean) * (a.y - mean) +
             (a.z - mean) * (a.z - mean) + (a.w - mean) * (a.w - mean) +
             (b.x - mean) * (b.x - mean) + (b.y - mean) * (b.y - mean) +
             (b.z - mean) * (b.z - mean) + (b.w - mean) * (b.w - mean);
  float rs = rsqrtf(wave_sum(vs) * (1.f / 512.f) + EPS);
  float4 za = f0[lane], zb = f0[lane + 64];
  float4 oa, ob2;
  oa.x = za.x + (a.x - mean) * rs; oa.y = za.y + (a.y - mean) * rs;
  oa.z = za.z + (a.z - mean) * rs; oa.w = za.w + (a.w - mean) * rs;
  ob2.x = zb.x + (b.x - mean) * rs; ob2.y = zb.y + (b.y - mean) * rs;
  ob2.z = zb.z + (b.z - mean) * rs; ob2.w = zb.w + (b.w - mean) * rs;
  f[lane] = oa; f[lane + 64] = ob2;
  unsigned short* dbp = featb + (size_t)row * 512;
  unsigned short t0[4] = {f2b(oa.x), f2b(oa.y), f2b(oa.z), f2b(oa.w)};
  unsigned short t1[4] = {f2b(ob2.x), f2b(ob2.y), f2b(ob2.z), f2b(ob2.w)};
  *(ushort2*)&dbp[lane * 4] = *(ushort2*)&t0[0];
  *(ushort2*)&dbp[lane * 4 + 2] = *(ushort2*)&t0[2];
  *(ushort2*)&dbp[256 + lane * 4] = *(ushort2*)&t1[0];
  *(ushort2*)&dbp[256 + lane * 4 + 2] = *(ushort2*)&t1[2];
}

__device__ void dist2_dev(int bx, const float* fq, const float* hi,
                          const float* ne, float* out) {
  const int row = bx * 4 + ((int)threadIdx.x >> 6);
  const int lane = threadIdx.x & 63;
  float f0 = fq[(size_t)row * 128 + lane];
  float f1 = fq[(size_t)row * 128 + 64 + lane];
  float mean = wave_sum(f0 + f1) * (1.f / 128.f);
  float vs = (f0 - mean) * (f0 - mean) + (f1 - mean) * (f1 - mean);
  float rs = rsqrtf(wave_sum(vs) * (1.f / 128.f) + EPS);
  f0 = (f0 - mean) * rs;
  f1 = (f1 - mean) * rs;
  float mp = 1e30f, mn = 1e30f;
  for (int p = 0; p < 40; ++p) {
    float h0 = hi[p * 128 + lane], h1 = hi[p * 128 + 64 + lane];
    float d0 = f0 - h0, d1 = f1 - h1;
    float d2 = wave_sum(d0 * d0 + d1 * d1);
    mp = fminf(mp, d2);
    float n0 = ne[p * 128 + lane], n1 = ne[p * 128 + 64 + lane];
    d0 = f0 - n0; d1 = f1 - n1;
    d2 = wave_sum(d0 * d0 + d1 * d1);
    mn = fminf(mn, d2);
  }
  if (lane == 0) {
    out[row * 2 + 0] = -sqrtf(mn);
    out[row * 2 + 1] = -sqrtf(mp);
  }
}

// ============ Cooperative mega-kernel: all 29 phases, 28 grid syncs ========
__global__ __launch_bounds__(256, 2) void fused_all(FusedArgs a) {
  __shared__ __align__(16) unsigned short sm[SM_SHORTS];
  cg::grid_group gg = cg::this_grid();
  const int b = blockIdx.x;

  for (int u = b; u < 2304 * 8; u += NBLK) conv_dev(u % 2304, u / 2304, a);
  __threadfence(); gg.sync();

  gemm32_dev<0, 1, 1, 0, 0, 0, 0>(sm, b & 63, b >> 6, a.x, nullptr,
                                  a.reduce_wb, a.reduce_b, nullptr, a.feat0_f,
                                  nullptr, 512, 768);
  __threadfence(); gg.sync();

  inorm512_dev(b, a.feat0_f, a.feat0_b, a.feat0_f);
  __threadfence(); gg.sync();

  for (int i = 0; i < 3; ++i) {
    const float* fin_f = (i == 0) ? a.feat0_f : a.feat_f;
    const unsigned short* fin_b = (i == 0) ? a.feat0_b : a.feat_b;

    for (int u = b; u < 1536; u += NBLK)
      gemm32_dev<0, 0, 0, 1, 0, 0, 1>(sm, u & 63, u >> 6, fin_b, nullptr,
                                      a.in_wb + (size_t)i * 1536 * 512,
                                      a.in_b + i * 1536, nullptr, nullptr,
                                      a.qkv_b, 1536, 512);
    __threadfence(); gg.sync();

    for (int u = b; u < 1024; u += NBLK)
      attn8_dev(sm, u & 31, (u >> 5) & 7, u >> 8, a.qkv_b, a.pm, a.po_b);
    __threadfence(); gg.sync();

    gemm32_dev<0, 0, 1, 0, 1, 1, 0>(sm, b & 63, b >> 6, a.po_b, a.pm,
                                    a.out_wb + (size_t)i * 512 * 512,
                                    a.out_b + i * 512, fin_f, a.tmp_f, nullptr,
                                    512, 512);
    __threadfence(); gg.sync();

    ln_res2_dev(b, a.feat_f, a.feat_b, a.tmp_f, a.ln1_w + i * 512,
                a.ln1_b + i * 512);
    __threadfence(); gg.sync();

    gemm32_dev<1, 0, 0, 1, 0, 0, 0>(sm, b & 63, b >> 6, a.feat_b, nullptr,
                                    a.ff1_wb + (size_t)i * 512 * 512,
                                    a.ff1_b + i * 512, nullptr, nullptr,
                                    a.relu_b, 512, 512);
    __threadfence(); gg.sync();

    gemm32_dev<0, 0, 1, 0, 0, 1, 0>(sm, b & 63, b >> 6, a.relu_b, nullptr,
                                    a.ff2_wb + (size_t)i * 512 * 512,
                                    a.ff2_b + i * 512, a.feat_f, a.tmp_f,
                                    nullptr, 512, 512);
    __threadfence(); gg.sync();

    ln_res2_dev(b, a.feat_f, a.feat_b, a.tmp_f, a.ln2_w + i * 512,
                a.ln2_b + i * 512);
    __threadfence(); gg.sync();
  }

  add_inorm_dev(b, a.feat_f, a.feat_b, a.feat0_f);
  __threadfence(); gg.sync();

  gemm32_dev<1, 0, 0, 1, 0, 0, 0>(sm, b & 63, b >> 6, a.feat_b, nullptr,
                                  a.mlp_w1b, a.mlp_b1, nullptr, nullptr,
                                  a.relu_b, 512, 512);
  __threadfence(); gg.sync();

  gemm32_dev<1, 0, 0, 1, 0, 0, 0>(sm, b & 63, b >> 6, a.relu_b, nullptr,
                                  a.mlp_w2b, a.mlp_b2, nullptr, nullptr,
                                  a.relu2_b, 512, 512);
  __threadfence(); gg.sync();

  if (b < 128)
    gemm32_dev<0, 0, 1, 0, 0, 0, 0>(sm, b & 63, b >> 6, a.relu2_b, nullptr,
                                    a.mlp_w3b, a.mlp_b3, nullptr, a.featq_f,
                                    nullptr, 128, 512);
  __threadfence(); gg.sync();

  dist2_dev(b, a.featq_f, a.hi, a.ne, a.out);
}

// ============ Fallback wrappers (exact R1 dispatch path) ===================
__global__ __launch_bounds__(256) void conv_wk(FusedArgs a) {
  conv_dev(blockIdx.x, blockIdx.y, a);
}

template <int RELU, int AF32, int OUT_F32, int OUT_BF16, int MERGE, int RESID,
          int SCALEQ>
__global__ __launch_bounds__(256) void gemm32k(
    const void* __restrict__ Aptr, const float* __restrict__ pmp,
    const unsigned short* __restrict__ W, const float* __restrict__ bias,
    const float* __restrict__ Rf, float* __restrict__ Cf,
    unsigned short* __restrict__ Cb, int N, int K) {
  __shared__ __align__(16) unsigned short sm[SM_SHORTS];
  gemm32_dev<RELU, AF32, OUT_F32, OUT_BF16, MERGE, RESID, SCALEQ>(
      sm, blockIdx.x, blockIdx.y, Aptr, pmp, W, bias, Rf, Cf, Cb, N, K);
}

__global__ __launch_bounds__(256) void attn8k(
    const unsigned short* __restrict__ qkv, float* __restrict__ pm,
    unsigned short* __restrict__ po) {
  __shared__ __align__(16) unsigned short sm[SM_SHORTS];
  attn8_dev(sm, blockIdx.x, blockIdx.y, blockIdx.z, qkv, pm, po);
}

__global__ __launch_bounds__(256) void inorm512k(float* d, unsigned short* db,
                                                 const float* s) {
  inorm512_dev(blockIdx.x, d, db, s);
}
__global__ __launch_bounds__(256) void ln_res2k(float* d, unsigned short* db,
                                                const float* s, const float* w,
                                                const float* bb) {
  ln_res2_dev(blockIdx.x, d, db, s, w, bb);
}
__global__ __launch_bounds__(256) void add_inormk(float* f, unsigned short* fb,
                                                  const float* f0) {
  add_inorm_dev(blockIdx.x, f, fb, f0);
}
__global__ __launch_bounds__(256) void dist2k(const float* fq, const float* hi,
                                              const float* ne, float* out) {
  dist2_dev(blockIdx.x, fq, hi, ne, out);
}

extern "C" void kernel_launch(void* const* d_in, const int* in_sizes, int n_in,
                              void* d_out, int out_size, void* d_ws, size_t ws_size,
                              hipStream_t stream) {
  const float* x        = (const float*)d_in[0];
  const float* reduce_w = (const float*)d_in[1];
  const float* reduce_b = (const float*)d_in[2];
  const float* in_w     = (const float*)d_in[3];
  const float* in_b     = (const float*)d_in[4];
  const float* out_w    = (const float*)d_in[5];
  const float* out_b    = (const float*)d_in[6];
  const float* ff1_w    = (const float*)d_in[7];
  const float* ff1_b    = (const float*)d_in[8];
  const float* ff2_w    = (const float*)d_in[9];
  const float* ff2_b    = (const float*)d_in[10];
  const float* ln1_w    = (const float*)d_in[11];
  const float* ln1_b    = (const float*)d_in[12];
  const float* ln2_w    = (const float*)d_in[13];
  const float* ln2_b    = (const float*)d_in[14];
  const float* mlp_w1   = (const float*)d_in[15];
  const float* mlp_b1   = (const float*)d_in[16];
  const float* mlp_w2   = (const float*)d_in[17];
  const float* mlp_b2   = (const float*)d_in[18];
  const float* mlp_w3   = (const float*)d_in[19];
  const float* mlp_b3   = (const float*)d_in[20];
  const float* hi       = (const float*)d_in[21];
  const float* ne       = (const float*)d_in[22];
  float* out = (float*)d_out;
  float* ws = (float*)d_ws;

  const size_t MD = (size_t)2048 * 512;
  float* feat0_f = ws;
  float* feat_f  = ws + MD;
  float* tmp_f   = ws + 2 * MD;
  float* pm      = ws + 3 * MD;
  unsigned short* u = (unsigned short*)(ws + 3 * MD + 65536);
  unsigned short* qkv_b   = u;
  unsigned short* feat0_b = u + 3 * MD;
  unsigned short* feat_b  = u + 4 * MD;
  unsigned short* relu_b  = u + 5 * MD;
  unsigned short* po_b    = u + 6 * MD;
  unsigned short* relu2_b = qkv_b;
  float* featq_f = tmp_f;

  unsigned short* wb = u + 10 * MD;
  unsigned short* reduce_wb = wb;
  unsigned short* in_wb     = wb + 393216;
  unsigned short* out_wb    = in_wb + 2359296;
  unsigned short* ff1_wb    = out_wb + 786432;
  unsigned short* ff2_wb    = ff1_wb + 786432;
  unsigned short* mlp_w1b   = ff2_wb + 786432;
  unsigned short* mlp_w2b   = mlp_w1b + 262144;
  unsigned short* mlp_w3b   = mlp_w2b + 262144;

  FusedArgs fa;
  fa.csrc[0] = reduce_w; fa.cdst[0] = reduce_wb; fa.cn[0] = 393216;
  fa.csrc[1] = in_w;     fa.cdst[1] = in_wb;     fa.cn[1] = 2359296;
  fa.csrc[2] = out_w;    fa.cdst[2] = out_wb;    fa.cn[2] = 786432;
  fa.csrc[3] = ff1_w;    fa.cdst[3] = ff1_wb;    fa.cn[3] = 786432;
  fa.csrc[4] = ff2_w;    fa.cdst[4] = ff2_wb;    fa.cn[4] = 786432;
  fa.csrc[5] = mlp_w1;   fa.cdst[5] = mlp_w1b;   fa.cn[5] = 262144;
  fa.csrc[6] = mlp_w2;   fa.cdst[6] = mlp_w2b;   fa.cn[6] = 262144;
  fa.csrc[7] = mlp_w3;   fa.cdst[7] = mlp_w3b;   fa.cn[7] = 65536;
  fa.x = x;
  fa.reduce_wb = reduce_wb; fa.reduce_b = reduce_b;
  fa.in_wb = in_wb;   fa.in_b = in_b;
  fa.out_wb = out_wb; fa.out_b = out_b;
  fa.ff1_wb = ff1_wb; fa.ff1_b = ff1_b;
  fa.ff2_wb = ff2_wb; fa.ff2_b = ff2_b;
  fa.ln1_w = ln1_w; fa.ln1_b = ln1_b;
  fa.ln2_w = ln2_w; fa.ln2_b = ln2_b;
  fa.mlp_w1b = mlp_w1b; fa.mlp_b1 = mlp_b1;
  fa.mlp_w2b = mlp_w2b; fa.mlp_b2 = mlp_b2;
  fa.mlp_w3b = mlp_w3b; fa.mlp_b3 = mlp_b3;
  fa.hi = hi; fa.ne = ne;
  fa.feat0_f = feat0_f; fa.feat0_b = feat0_b;
  fa.feat_f = feat_f;   fa.feat_b = feat_b;
  fa.tmp_f = tmp_f;     fa.pm = pm;
  fa.qkv_b = qkv_b; fa.relu_b = relu_b; fa.po_b = po_b; fa.relu2_b = relu2_b;
  fa.featq_f = featq_f; fa.out = out;

  void* kargs[] = {(void*)&fa};
  hipError_t err = hipLaunchCooperativeKernel(
      reinterpret_cast<const void*>(&fused_all), dim3(NBLK), dim3(256), kargs,
      0, stream);
  if (err == hipSuccess) return;

  // -------- fallback: proven R1 multi-dispatch path --------
  dim3 blk(256);
  conv_wk<<<dim3(2304, 8), blk, 0, stream>>>(fa);
  gemm32k<0, 1, 1, 0, 0, 0, 0><<<dim3(64, 8), blk, 0, stream>>>(
      x, nullptr, reduce_wb, reduce_b, nullptr, feat0_f, nullptr, 512, 768);
  inorm512k<<<512, blk, 0, stream>>>(feat0_f, feat0_b, feat0_f);

  for (int i = 0; i < 3; ++i) {
    const float* fin_f = (i == 0) ? feat0_f : feat_f;
    const unsigned short* fin_b = (i == 0) ? feat0_b : feat_b;
    gemm32k<0, 0, 0, 1, 0, 0, 1><<<dim3(64, 24), blk, 0, stream>>>(
        fin_b, nullptr, in_wb + (size_t)i * 1536 * 512, in_b + i * 1536,
        nullptr, nullptr, qkv_b, 1536, 512);
    attn8k<<<dim3(32, 8, 4), blk, 0, stream>>>(qkv_b, pm, po_b);
    gemm32k<0, 0, 1, 0, 1, 1, 0><<<dim3(64, 8), blk, 0, stream>>>(
        po_b, pm, out_wb + (size_t)i * 512 * 512, out_b + i * 512,
        fin_f, tmp_f, nullptr, 512, 512);
    ln_res2k<<<512, blk, 0, stream>>>(feat_f, feat_b, tmp_f,
                                      ln1_w + i * 512, ln1_b + i * 512);
    gemm32k<1, 0, 0, 1, 0, 0, 0><<<dim3(64, 8), blk, 0, stream>>>(
        feat_b, nullptr, ff1_wb + (size_t)i * 512 * 512, ff1_b + i * 512,
        nullptr, nullptr, relu_b, 512, 512);
    gemm32k<0, 0, 1, 0, 0, 1, 0><<<dim3(64, 8), blk, 0, stream>>>(
        relu_b, nullptr, ff2_wb + (size_t)i * 512 * 512, ff2_b + i * 512,
        feat_f, tmp_f, nullptr, 512, 512);
    ln_res2k<<<512, blk, 0, stream>>>(feat_f, feat_b, tmp_f,
                                      ln2_w + i * 512, ln2_b + i * 512);
  }

  add_inormk<<<512, blk, 0, stream>>>(feat_f, feat_b, feat0_f);
  gemm32k<1, 0, 0, 1, 0, 0, 0><<<dim3(64, 8), blk, 0, stream>>>(
      feat_b, nullptr, mlp_w1b, mlp_b1, nullptr, nullptr, relu_b, 512, 512);
  gemm32k<1, 0, 0, 1, 0, 0, 0><<<dim3(64, 8), blk, 0, stream>>>(
      relu_b, nullptr, mlp_w2b, mlp_b2, nullptr, nullptr, relu2_b, 512, 512);
  gemm32k<0, 0, 1, 0, 0, 0, 0><<<dim3(64, 2), blk, 0, stream>>>(
      relu2_b, nullptr, mlp_w3b, mlp_b3, nullptr, featq_f, nullptr, 128, 512);
  dist2k<<<512, blk, 0, stream>>>(featq_f, hi, ne, out);
}

// Round 9
// 359.666 us; speedup vs baseline: 9.0092x; 9.0092x over previous
//
#include <hip/hip_runtime.h>
#include <math.h>
#include <cstddef>

#define EPS 1e-5f

typedef __attribute__((ext_vector_type(8))) short bf16x8;
typedef __attribute__((ext_vector_type(4))) float f32x4;

__device__ __forceinline__ float wave_sum(float v) {
#pragma unroll
  for (int o = 32; o > 0; o >>= 1) v += __shfl_xor(v, o, 64);
  return v;
}

// fp32 -> bf16 bits, round-to-nearest-even (finite inputs only)
__device__ __forceinline__ unsigned short f2b(float f) {
  union { float f; unsigned int u; } v; v.f = f;
  unsigned int r = (v.u + 0x7FFFu + ((v.u >> 16) & 1u)) >> 16;
  return (unsigned short)r;
}
__device__ __forceinline__ float b2f(unsigned short u) {
  union { unsigned int u; float f; } v; v.u = ((unsigned int)u) << 16;
  return v.f;
}

// packed f32x2 -> bf16x2 (RNE), gfx950 HW instruction
__device__ __forceinline__ unsigned int pk2(float lo, float hi) {
  unsigned int r;
  asm volatile("v_cvt_pk_bf16_f32 %0, %1, %2" : "=v"(r) : "v"(lo), "v"(hi));
  return r;
}

// ============ Weight pre-conversion: fp32 -> bf16, 8 arrays in one launch ==
struct WConvArgs {
  const float* src[8];
  unsigned short* dst[8];
  int n[8];
};
__global__ __launch_bounds__(256) void conv_w(WConvArgs a) {
  const int arr = blockIdx.y;
  const int i = (blockIdx.x * 256 + threadIdx.x) * 4;
  if (i >= a.n[arr]) return;
  const float4 f = *(const float4*)(a.src[arr] + i);
  unsigned short t[4] = {f2b(f.x), f2b(f.y), f2b(f.z), f2b(f.w)};
  unsigned short* d = a.dst[arr] + i;
  *(ushort2*)d = *(ushort2*)&t[0];
  *(ushort2*)(d + 2) = *(ushort2*)&t[2];
}

// ============ MFMA GEMM: C[M,N] = A[M,K] @ W[N,K]^T + bias =================
// W pre-converted bf16. 32x64 tile, 4 waves. Double-buffered LDS, register
// prefetch, 1 barrier/K-step.
// MERGE: A = attention split-merge: sum of 2 unnormalized partials / sum(l).
// RESID: epilogue adds Rf (residual) before store.
// SCALEQ: multiply columns [0,512) by 0.125 (q scale for attention).
template <int RELU, int AF32, int OUT_F32, int OUT_BF16, int MERGE, int RESID,
          int SCALEQ>
__global__ __launch_bounds__(256) void gemm32(
    const void* __restrict__ Aptr, const float* __restrict__ pmp,
    const unsigned short* __restrict__ W, const float* __restrict__ bias,
    const float* __restrict__ Rf, float* __restrict__ Cf,
    unsigned short* __restrict__ Cb, int M, int N, int K) {
  __shared__ __align__(16) unsigned short As[2][32][72];
  __shared__ __align__(16) unsigned short Ws[2][64][72];
  const int tid = threadIdx.x;
  const int wid = tid >> 6, lane = tid & 63;
  const int ln = lane & 15, quad = lane >> 4;
  const int m0 = blockIdx.x * 32, n0 = blockIdx.y * 64;
  const int arow = tid >> 3, aseg = tid & 7;   // A: 8 threads/row, 8 elems
  const int wrow = tid >> 2, wseg = tid & 3;   // W: 4 threads/row, 16 elems
  const int KS = K >> 6;

  bf16x8 ra;
  float4 ra32[2];
  bf16x8 rwb0, rwb1;
  bf16x8 rp[2];
  float rl;

  auto load_tile = [&](int ks) {
    const int k0 = ks * 64;
    if (MERGE) {
      const int h = ks;  // K=512, 8 heads of 64: head index == K-step
      const int row = m0 + arow;
      rl = 0.f;
#pragma unroll
      for (int s = 0; s < 2; ++s) {
        const size_t b = (size_t)((s * 8 + h) * 2048 + row);
        rl += pmp[b];
        rp[s] = *(const bf16x8*)((const unsigned short*)Aptr + b * 64 + aseg * 8);
      }
    } else if (AF32) {
      const float* ap = (const float*)Aptr + (size_t)(m0 + arow) * K + k0 + aseg * 8;
      ra32[0] = *(const float4*)ap;
      ra32[1] = *(const float4*)(ap + 4);
    } else {
      ra = *(const bf16x8*)((const unsigned short*)Aptr +
                            (size_t)(m0 + arow) * K + k0 + aseg * 8);
    }
    const unsigned short* wp = W + (size_t)(n0 + wrow) * K + k0 + wseg * 16;
    rwb0 = *(const bf16x8*)wp;
    rwb1 = *(const bf16x8*)(wp + 8);
  };

  auto store_tile = [&](int buf) {
    if (MERGE) {
      float inv = 1.f / rl;
      unsigned short ta[8];
#pragma unroll
      for (int j = 0; j < 8; ++j) {
        float s = b2f((unsigned short)rp[0][j]) + b2f((unsigned short)rp[1][j]);
        ta[j] = f2b(inv * s);
      }
      *(bf16x8*)&As[buf][arow][aseg * 8] = *(const bf16x8*)&ta[0];
    } else if (AF32) {
      unsigned short ta[8];
      ta[0] = f2b(ra32[0].x); ta[1] = f2b(ra32[0].y);
      ta[2] = f2b(ra32[0].z); ta[3] = f2b(ra32[0].w);
      ta[4] = f2b(ra32[1].x); ta[5] = f2b(ra32[1].y);
      ta[6] = f2b(ra32[1].z); ta[7] = f2b(ra32[1].w);
      *(bf16x8*)&As[buf][arow][aseg * 8] = *(const bf16x8*)&ta[0];
    } else {
      *(bf16x8*)&As[buf][arow][aseg * 8] = ra;
    }
    *(bf16x8*)&Ws[buf][wrow][wseg * 16] = rwb0;
    *(bf16x8*)&Ws[buf][wrow][wseg * 16 + 8] = rwb1;
  };

  f32x4 acc[2];
  acc[0] = (f32x4){0.f, 0.f, 0.f, 0.f};
  acc[1] = (f32x4){0.f, 0.f, 0.f, 0.f};

  const int mrow = (wid & 1) * 16, nh = wid >> 1;

  load_tile(0);
  store_tile(0);
  __syncthreads();

#pragma unroll 1
  for (int ks = 0; ks < KS; ++ks) {
    const int cur = ks & 1;
    if (ks + 1 < KS) load_tile(ks + 1);
#pragma unroll
    for (int kc = 0; kc < 2; ++kc) {
      bf16x8 af = *(const bf16x8*)&As[cur][mrow + ln][kc * 32 + quad * 8];
#pragma unroll
      for (int nt = 0; nt < 2; ++nt) {
        bf16x8 wf = *(const bf16x8*)&Ws[cur][nh * 32 + nt * 16 + ln][kc * 32 + quad * 8];
        acc[nt] = __builtin_amdgcn_mfma_f32_16x16x32_bf16(af, wf, acc[nt], 0, 0, 0);
      }
    }
    if (ks + 1 < KS) store_tile(cur ^ 1);
    __syncthreads();
  }

  const int gm = m0 + mrow + quad * 4;
  const float qs = (SCALEQ && n0 < 512) ? 0.125f : 1.f;
#pragma unroll
  for (int nt = 0; nt < 2; ++nt) {
    const int gn = n0 + nh * 32 + nt * 16 + ln;
    float bv = bias[gn];
#pragma unroll
    for (int r = 0; r < 4; ++r) {
      float v = acc[nt][r] + bv;
      if (SCALEQ) v *= qs;
      if (RELU) v = fmaxf(v, 0.f);
      if (RESID) v += Rf[(size_t)(gm + r) * N + gn];
      if (OUT_F32) Cf[(size_t)(gm + r) * N + gn] = v;
      if (OUT_BF16) Cb[(size_t)(gm + r) * N + gn] = f2b(v);
    }
  }
}

// ============ Flash attention v8s: swapped QK^T, 2-way key split ===========
// grid (32 q-tiles, 8 heads, 2 splits) = 512 blocks = 2/CU resident.
// 16 K-tiles of 64 per block (vs 8 at 4 splits): halves po/pm traffic and
// prologue/epilogue count; same inner loop, same occupancy.
__global__ __launch_bounds__(256) void flash_attn8(
    const unsigned short* __restrict__ qkv, float* __restrict__ pm,
    unsigned short* __restrict__ po) {
  __shared__ __align__(16) unsigned short Ks[64][72];
  __shared__ __align__(16) unsigned short Vt[64][72];
  __shared__ __align__(16) unsigned int Pp[64][36];  // packed P, stride 144B
  const int qt = blockIdx.x, h = blockIdx.y, sp = blockIdx.z;
  const int tid = threadIdx.x;
  const int wid = tid >> 6, lane = tid & 63;
  const int ln = lane & 15, quad = lane >> 4;
  const int wq0 = wid * 16;

  bf16x8 aq[2];
  {
    const unsigned short* qp =
        qkv + (size_t)(qt * 64 + wq0 + ln) * 1536 + h * 64 + quad * 8;
    aq[0] = *(const bf16x8*)qp;
    aq[1] = *(const bf16x8*)(qp + 32);
  }

  const int key = tid >> 2, seg = tid & 3;  // K staging
  bf16x8 rk0, rk1;
  unsigned short tv[16];

  auto load_kv = [&](int t) {
    const int g = sp * 16 + t;
    const unsigned short* kr =
        qkv + (size_t)(g * 64 + key) * 1536 + 512 + h * 64 + seg * 16;
    rk0 = *(const bf16x8*)kr;
    rk1 = *(const bf16x8*)(kr + 8);
#pragma unroll
    for (int j = 0; j < 16; ++j)
      tv[j] = qkv[(size_t)(g * 64 + wid * 16 + j) * 1536 + 1024 + h * 64 + lane];
  };
  auto store_kv = [&]() {
    *(bf16x8*)&Ks[key][seg * 16] = rk0;
    *(bf16x8*)&Ks[key][seg * 16 + 8] = rk1;
    *(bf16x8*)&Vt[lane][wid * 16] = *(const bf16x8*)&tv[0];
    *(bf16x8*)&Vt[lane][wid * 16 + 8] = *(const bf16x8*)&tv[8];
  };

  float l_r = 0.f;  // partial denom for q-row wq0+ln over this lane's keys
  f32x4 acc_o[4];
#pragma unroll
  for (int nt = 0; nt < 4; ++nt) acc_o[nt] = (f32x4){0.f, 0.f, 0.f, 0.f};

  load_kv(0);
  store_kv();
  __syncthreads();

#pragma unroll 1
  for (int t = 0; t < 16; ++t) {
    if (t + 1 < 16) load_kv(t + 1);  // global latency overlaps compute

    f32x4 s_acc[4];
#pragma unroll
    for (int nt = 0; nt < 4; ++nt) s_acc[nt] = (f32x4){0.f, 0.f, 0.f, 0.f};
#pragma unroll
    for (int nt = 0; nt < 4; ++nt) {
      bf16x8 kf0 = *(const bf16x8*)&Ks[nt * 16 + ln][quad * 8];
      bf16x8 kf1 = *(const bf16x8*)&Ks[nt * 16 + ln][32 + quad * 8];
      // swapped operands: D[key][q] — A=K rows(keys), B=Q rows(q)
      s_acc[nt] = __builtin_amdgcn_mfma_f32_16x16x32_bf16(kf0, aq[0], s_acc[nt], 0, 0, 0);
      s_acc[nt] = __builtin_amdgcn_mfma_f32_16x16x32_bf16(kf1, aq[1], s_acc[nt], 0, 0, 0);
    }

    // p = exp(s); pack pairs of consecutive keys; 4x ds_write_b64
#pragma unroll
    for (int nt = 0; nt < 4; ++nt) {
      float p0 = __expf(s_acc[nt][0]);
      float p1 = __expf(s_acc[nt][1]);
      float p2 = __expf(s_acc[nt][2]);
      float p3 = __expf(s_acc[nt][3]);
      l_r += (p0 + p1) + (p2 + p3);
      uint2 w;
      w.x = pk2(p0, p1);  // keys nt*16+quad*4 + {0,1}
      w.y = pk2(p2, p3);  // keys nt*16+quad*4 + {2,3}
      *(uint2*)&Pp[wq0 + ln][nt * 8 + quad * 2] = w;
    }

#pragma unroll
    for (int kc = 0; kc < 2; ++kc) {
      bf16x8 pf = *(const bf16x8*)&Pp[wq0 + ln][kc * 16 + quad * 4];
#pragma unroll
      for (int nt = 0; nt < 4; ++nt) {
        bf16x8 vf = *(const bf16x8*)&Vt[nt * 16 + ln][kc * 32 + quad * 8];
        acc_o[nt] = __builtin_amdgcn_mfma_f32_16x16x32_bf16(pf, vf, acc_o[nt], 0, 0, 0);
      }
    }
    __syncthreads();  // all reads of Ks/Vt complete before overwrite
    if (t + 1 < 16) {
      store_kv();
      __syncthreads();
    }
  }

  // epilogue: l lives per-ln, partial over quads -> 2-shuffle reduce
  const size_t base = (size_t)((sp * 8 + h) * 2048 + qt * 64);
  float l = l_r;
  l += __shfl_xor(l, 16, 64);
  l += __shfl_xor(l, 32, 64);
  if (quad == 0) pm[base + wq0 + ln] = l;
#pragma unroll
  for (int r = 0; r < 4; ++r) {
    const size_t row = base + wq0 + quad * 4 + r;
#pragma unroll
    for (int nt = 0; nt < 4; ++nt)
      po[row * 64 + nt * 16 + ln] = f2b(acc_o[nt][r]);
  }
}

// ============ Row-wise kernels (one wave per row of 2048) ==================
__global__ __launch_bounds__(256) void inorm512(float* __restrict__ dst,
                                                unsigned short* __restrict__ dstb,
                                                const float* __restrict__ src) {
  const int row = blockIdx.x * 4 + (threadIdx.x >> 6);
  const int lane = threadIdx.x & 63;
  const float4* s = (const float4*)(src + (size_t)row * 512);
  float4 a = s[lane], b = s[lane + 64];
  float sum = a.x + a.y + a.z + a.w + b.x + b.y + b.z + b.w;
  float mean = wave_sum(sum) * (1.f / 512.f);
  float vs = (a.x - mean) * (a.x - mean) + (a.y - mean) * (a.y - mean) +
             (a.z - mean) * (a.z - mean) + (a.w - mean) * (a.w - mean) +
             (b.x - mean) * (b.x - mean) + (b.y - mean) * (b.y - mean) +
             (b.z - mean) * (b.z - mean) + (b.w - mean) * (b.w - mean);
  float rs = rsqrtf(wave_sum(vs) * (1.f / 512.f) + EPS);
  float4 oa, obv;
  oa.x = (a.x - mean) * rs; oa.y = (a.y - mean) * rs;
  oa.z = (a.z - mean) * rs; oa.w = (a.w - mean) * rs;
  obv.x = (b.x - mean) * rs; obv.y = (b.y - mean) * rs;
  obv.z = (b.z - mean) * rs; obv.w = (b.w - mean) * rs;
  float4* d = (float4*)(dst + (size_t)row * 512);
  d[lane] = oa; d[lane + 64] = obv;
  unsigned short* db = dstb + (size_t)row * 512;
  unsigned short t0[4] = {f2b(oa.x), f2b(oa.y), f2b(oa.z), f2b(oa.w)};
  unsigned short t1[4] = {f2b(obv.x), f2b(obv.y), f2b(obv.z), f2b(obv.w)};
  *(ushort2*)&db[lane * 4] = *(ushort2*)&t0[0];
  *(ushort2*)&db[lane * 4 + 2] = *(ushort2*)&t0[2];
  *(ushort2*)&db[256 + lane * 4] = *(ushort2*)&t1[0];
  *(ushort2*)&db[256 + lane * 4 + 2] = *(ushort2*)&t1[2];
}

// LN over rows of src (already residual-summed); writes f32 + bf16
__global__ __launch_bounds__(256) void ln_res2(float* __restrict__ dst,
                                               unsigned short* __restrict__ dstb,
                                               const float* __restrict__ src,
                                               const float* __restrict__ w,
                                               const float* __restrict__ bb) {
  const int row = blockIdx.x * 4 + (threadIdx.x >> 6);
  const int lane = threadIdx.x & 63;
  const float4* xs = (const float4*)(src + (size_t)row * 512);
  float4 a = xs[lane], b = xs[lane + 64];
  float sum = a.x + a.y + a.z + a.w + b.x + b.y + b.z + b.w;
  float mean = wave_sum(sum) * (1.f / 512.f);
  float vs = (a.x - mean) * (a.x - mean) + (a.y - mean) * (a.y - mean) +
             (a.z - mean) * (a.z - mean) + (a.w - mean) * (a.w - mean) +
             (b.x - mean) * (b.x - mean) + (b.y - mean) * (b.y - mean) +
             (b.z - mean) * (b.z - mean) + (b.w - mean) * (b.w - mean);
  float rs = rsqrtf(wave_sum(vs) * (1.f / 512.f) + EPS);
  float4 wa = ((const float4*)w)[lane], wb = ((const float4*)w)[lane + 64];
  float4 ba = ((const float4*)bb)[lane], bbv = ((const float4*)bb)[lane + 64];
  float4 oa, ob2;
  oa.x = (a.x - mean) * rs * wa.x + ba.x; oa.y = (a.y - mean) * rs * wa.y + ba.y;
  oa.z = (a.z - mean) * rs * wa.z + ba.z; oa.w = (a.w - mean) * rs * wa.w + ba.w;
  ob2.x = (b.x - mean) * rs * wb.x + bbv.x; ob2.y = (b.y - mean) * rs * wb.y + bbv.y;
  ob2.z = (b.z - mean) * rs * wb.z + bbv.z; ob2.w = (b.w - mean) * rs * wb.w + bbv.w;
  float4* d = (float4*)(dst + (size_t)row * 512);
  d[lane] = oa; d[lane + 64] = ob2;
  unsigned short* dbp = dstb + (size_t)row * 512;
  unsigned short t0[4] = {f2b(oa.x), f2b(oa.y), f2b(oa.z), f2b(oa.w)};
  unsigned short t1[4] = {f2b(ob2.x), f2b(ob2.y), f2b(ob2.z), f2b(ob2.w)};
  *(ushort2*)&dbp[lane * 4] = *(ushort2*)&t0[0];
  *(ushort2*)&dbp[lane * 4 + 2] = *(ushort2*)&t0[2];
  *(ushort2*)&dbp[256 + lane * 4] = *(ushort2*)&t1[0];
  *(ushort2*)&dbp[256 + lane * 4 + 2] = *(ushort2*)&t1[2];
}

__global__ __launch_bounds__(256) void add_inorm(float* __restrict__ feat,
                                                 unsigned short* __restrict__ featb,
                                                 const float* __restrict__ feat0) {
  const int row = blockIdx.x * 4 + (threadIdx.x >> 6);
  const int lane = threadIdx.x & 63;
  float4* f = (float4*)(feat + (size_t)row * 512);
  const float4* f0 = (const float4*)(feat0 + (size_t)row * 512);
  float4 a = f[lane], b = f[lane + 64];
  float sum = a.x + a.y + a.z + a.w + b.x + b.y + b.z + b.w;
  float mean = wave_sum(sum) * (1.f / 512.f);
  float vs = (a.x - mean) * (a.x - mean) + (a.y - mean) * (a.y - mean) +
             (a.z - mean) * (a.z - mean) + (a.w - mean) * (a.w - mean) +
             (b.x - mean) * (b.x - mean) + (b.y - mean) * (b.y - mean) +
             (b.z - mean) * (b.z - mean) + (b.w - mean) * (b.w - mean);
  float rs = rsqrtf(wave_sum(vs) * (1.f / 512.f) + EPS);
  float4 za = f0[lane], zb = f0[lane + 64];
  float4 oa, ob2;
  oa.x = za.x + (a.x - mean) * rs; oa.y = za.y + (a.y - mean) * rs;
  oa.z = za.z + (a.z - mean) * rs; oa.w = za.w + (a.w - mean) * rs;
  ob2.x = zb.x + (b.x - mean) * rs; ob2.y = zb.y + (b.y - mean) * rs;
  ob2.z = zb.z + (b.z - mean) * rs; ob2.w = zb.w + (b.w - mean) * rs;
  f[lane] = oa; f[lane + 64] = ob2;
  unsigned short* dbp = featb + (size_t)row * 512;
  unsigned short t0[4] = {f2b(oa.x), f2b(oa.y), f2b(oa.z), f2b(oa.w)};
  unsigned short t1[4] = {f2b(ob2.x), f2b(ob2.y), f2b(ob2.z), f2b(ob2.w)};
  *(ushort2*)&dbp[lane * 4] = *(ushort2*)&t0[0];
  *(ushort2*)&dbp[lane * 4 + 2] = *(ushort2*)&t0[2];
  *(ushort2*)&dbp[256 + lane * 4] = *(ushort2*)&t1[0];
  *(ushort2*)&dbp[256 + lane * 4 + 2] = *(ushort2*)&t1[2];
}

// dist with fused inorm128: one wave per row
__global__ __launch_bounds__(256) void dist2(const float* __restrict__ fq,
                                             const float* __restrict__ hi,
                                             const float* __restrict__ ne,
                                             float* __restrict__ out) {
  const int row = blockIdx.x * 4 + (threadIdx.x >> 6);
  const int lane = threadIdx.x & 63;
  float f0 = fq[(size_t)row * 128 + lane];
  float f1 = fq[(size_t)row * 128 + 64 + lane];
  float mean = wave_sum(f0 + f1) * (1.f / 128.f);
  float vs = (f0 - mean) * (f0 - mean) + (f1 - mean) * (f1 - mean);
  float rs = rsqrtf(wave_sum(vs) * (1.f / 128.f) + EPS);
  f0 = (f0 - mean) * rs;
  f1 = (f1 - mean) * rs;
  float mp = 1e30f, mn = 1e30f;
  for (int p = 0; p < 40; ++p) {
    float h0 = hi[p * 128 + lane], h1 = hi[p * 128 + 64 + lane];
    float d0 = f0 - h0, d1 = f1 - h1;
    float d2 = wave_sum(d0 * d0 + d1 * d1);
    mp = fminf(mp, d2);
    float n0 = ne[p * 128 + lane], n1 = ne[p * 128 + 64 + lane];
    d0 = f0 - n0; d1 = f1 - n1;
    d2 = wave_sum(d0 * d0 + d1 * d1);
    mn = fminf(mn, d2);
  }
  if (lane == 0) {
    out[row * 2 + 0] = -sqrtf(mn);
    out[row * 2 + 1] = -sqrtf(mp);
  }
}

extern "C" void kernel_launch(void* const* d_in, const int* in_sizes, int n_in,
                              void* d_out, int out_size, void* d_ws, size_t ws_size,
                              hipStream_t stream) {
  const float* x        = (const float*)d_in[0];
  const float* reduce_w = (const float*)d_in[1];
  const float* reduce_b = (const float*)d_in[2];
  const float* in_w     = (const float*)d_in[3];
  const float* in_b     = (const float*)d_in[4];
  const float* out_w    = (const float*)d_in[5];
  const float* out_b    = (const float*)d_in[6];
  const float* ff1_w    = (const float*)d_in[7];
  const float* ff1_b    = (const float*)d_in[8];
  const float* ff2_w    = (const float*)d_in[9];
  const float* ff2_b    = (const float*)d_in[10];
  const float* ln1_w    = (const float*)d_in[11];
  const float* ln1_b    = (const float*)d_in[12];
  const float* ln2_w    = (const float*)d_in[13];
  const float* ln2_b    = (const float*)d_in[14];
  const float* mlp_w1   = (const float*)d_in[15];
  const float* mlp_b1   = (const float*)d_in[16];
  const float* mlp_w2   = (const float*)d_in[17];
  const float* mlp_b2   = (const float*)d_in[18];
  const float* mlp_w3   = (const float*)d_in[19];
  const float* mlp_b3   = (const float*)d_in[20];
  const float* hi       = (const float*)d_in[21];
  const float* ne       = (const float*)d_in[22];
  float* out = (float*)d_out;
  float* ws = (float*)d_ws;

  const size_t MD = (size_t)2048 * 512;  // 1M elems
  float* feat0_f = ws;                // MD
  float* feat_f  = ws + MD;           // MD
  float* tmp_f   = ws + 2 * MD;       // MD
  float* pm      = ws + 3 * MD;       // 2*8*2048 = 32768 f32 (65536 reserved)
  unsigned short* u = (unsigned short*)(ws + 3 * MD + 65536);
  unsigned short* qkv_b   = u;            // 3*MD
  unsigned short* feat0_b = u + 3 * MD;   // MD
  unsigned short* feat_b  = u + 4 * MD;   // MD
  unsigned short* relu_b  = u + 5 * MD;   // MD
  unsigned short* po_b    = u + 6 * MD;   // 2*8*2048*64 = 2*MD (4*MD reserved)
  unsigned short* relu2_b = qkv_b;        // alias: attention done by then
  float* featq_f = tmp_f;

  // bf16 weight region
  unsigned short* wb = u + 10 * MD;
  unsigned short* reduce_wb = wb;                   // 393216
  unsigned short* in_wb     = wb + 393216;          // 2359296
  unsigned short* out_wb    = in_wb + 2359296;      // 786432
  unsigned short* ff1_wb    = out_wb + 786432;      // 786432
  unsigned short* ff2_wb    = ff1_wb + 786432;      // 786432
  unsigned short* mlp_w1b   = ff2_wb + 786432;      // 262144
  unsigned short* mlp_w2b   = mlp_w1b + 262144;     // 262144
  unsigned short* mlp_w3b   = mlp_w2b + 262144;     // 65536

  dim3 blk(256);
  WConvArgs wa;
  wa.src[0] = reduce_w; wa.dst[0] = reduce_wb; wa.n[0] = 393216;
  wa.src[1] = in_w;     wa.dst[1] = in_wb;     wa.n[1] = 2359296;
  wa.src[2] = out_w;    wa.dst[2] = out_wb;    wa.n[2] = 786432;
  wa.src[3] = ff1_w;    wa.dst[3] = ff1_wb;    wa.n[3] = 786432;
  wa.src[4] = ff2_w;    wa.dst[4] = ff2_wb;    wa.n[4] = 786432;
  wa.src[5] = mlp_w1;   wa.dst[5] = mlp_w1b;   wa.n[5] = 262144;
  wa.src[6] = mlp_w2;   wa.dst[6] = mlp_w2b;   wa.n[6] = 262144;
  wa.src[7] = mlp_w3;   wa.dst[7] = mlp_w3b;   wa.n[7] = 65536;
  conv_w<<<dim3(2304, 8), blk, 0, stream>>>(wa);

  gemm32<0, 1, 1, 0, 0, 0, 0><<<dim3(64, 8), blk, 0, stream>>>(
      x, nullptr, reduce_wb, reduce_b, nullptr, feat0_f, nullptr, 2048, 512, 768);
  inorm512<<<512, blk, 0, stream>>>(feat0_f, feat0_b, feat0_f);

  for (int i = 0; i < 3; ++i) {
    const float* fin_f = (i == 0) ? feat0_f : feat_f;
    const unsigned short* fin_b = (i == 0) ? feat0_b : feat_b;
    gemm32<0, 0, 0, 1, 0, 0, 1><<<dim3(64, 24), blk, 0, stream>>>(
        fin_b, nullptr, in_wb + (size_t)i * 1536 * 512, in_b + i * 1536,
        nullptr, nullptr, qkv_b, 2048, 1536, 512);
    flash_attn8<<<dim3(32, 8, 2), blk, 0, stream>>>(qkv_b, pm, po_b);
    gemm32<0, 0, 1, 0, 1, 1, 0><<<dim3(64, 8), blk, 0, stream>>>(
        po_b, pm, out_wb + (size_t)i * 512 * 512, out_b + i * 512,
        fin_f, tmp_f, nullptr, 2048, 512, 512);
    ln_res2<<<512, blk, 0, stream>>>(feat_f, feat_b, tmp_f,
                                     ln1_w + i * 512, ln1_b + i * 512);
    gemm32<1, 0, 0, 1, 0, 0, 0><<<dim3(64, 8), blk, 0, stream>>>(
        feat_b, nullptr, ff1_wb + (size_t)i * 512 * 512, ff1_b + i * 512,
        nullptr, nullptr, relu_b, 2048, 512, 512);
    gemm32<0, 0, 1, 0, 0, 1, 0><<<dim3(64, 8), blk, 0, stream>>>(
        relu_b, nullptr, ff2_wb + (size_t)i * 512 * 512, ff2_b + i * 512,
        feat_f, tmp_f, nullptr, 2048, 512, 512);
    ln_res2<<<512, blk, 0, stream>>>(feat_f, feat_b, tmp_f,
                                     ln2_w + i * 512, ln2_b + i * 512);
  }

  add_inorm<<<512, blk, 0, stream>>>(feat_f, feat_b, feat0_f);
  gemm32<1, 0, 0, 1, 0, 0, 0><<<dim3(64, 8), blk, 0, stream>>>(
      feat_b, nullptr, mlp_w1b, mlp_b1, nullptr, nullptr, relu_b, 2048, 512, 512);
  gemm32<1, 0, 0, 1, 0, 0, 0><<<dim3(64, 8), blk, 0, stream>>>(
      relu_b, nullptr, mlp_w2b, mlp_b2, nullptr, nullptr, relu2_b, 2048, 512, 512);
  gemm32<0, 0, 1, 0, 0, 0, 0><<<dim3(64, 2), blk, 0, stream>>>(
      relu2_b, nullptr, mlp_w3b, mlp_b3, nullptr, featq_f, nullptr, 2048, 128, 512);
  dist2<<<512, blk, 0, stream>>>(featq_f, hi, ne, out);
}